// Round 2
// 647.465 us; speedup vs baseline: 1.0794x; 1.0794x over previous
//
#include <hip/hip_runtime.h>
#include <hip/hip_fp16.h>
#include <cstdint>

#define MB 8
#define TT 2048
#define DIMK 1024
#define CC 128
#define NG 32                 /* scan groups per batch, 4 rows each */
#define MROWS (MB*TT)         /* 16384 */
#define NPROJ 576
#define YSTR 576

using bf16x8 = __attribute__((__ext_vector_type__(8))) __bf16;
using f32x4v = __attribute__((__ext_vector_type__(4))) float;

__device__ __forceinline__ unsigned short f2b(float f) {
    unsigned u = __float_as_uint(f);
    u += 0x7fffu + ((u >> 16) & 1u);
    return (unsigned short)(u >> 16);
}

// ---------------------------------------------------------------------------
// Casts / packing
// ---------------------------------------------------------------------------
__global__ __launch_bounds__(256) void cast_x_kernel(
    const float* __restrict__ in, unsigned short* __restrict__ outp)
{
    size_t i = ((size_t)blockIdx.x * 256 + threadIdx.x) * 8;
    float4 a = *(const float4*)(in + i);
    float4 b = *(const float4*)(in + i + 4);
    uint4 r;
    r.x = f2b(a.x) | ((unsigned)f2b(a.y) << 16);
    r.y = f2b(a.z) | ((unsigned)f2b(a.w) << 16);
    r.z = f2b(b.x) | ((unsigned)f2b(b.y) << 16);
    r.w = f2b(b.z) | ((unsigned)f2b(b.w) << 16);
    *(uint4*)(outp + i) = r;
}

// WcatT[n][k] bf16, n in [0,576): 0-127 Wq, ... 512 Wa, 513 Wb, rest 0.
__global__ __launch_bounds__(256) void pack_wt(
    const float* __restrict__ Wq, const float* __restrict__ Wk,
    const float* __restrict__ Wv, const float* __restrict__ Wg,
    const float* __restrict__ Wa, const float* __restrict__ Wb,
    unsigned short* __restrict__ WcatT)
{
    int idx = blockIdx.x * 256 + threadIdx.x;
    if (idx >= NPROJ * DIMK) return;
    int n = idx >> 10, k = idx & 1023;
    float v = 0.f;
    if      (n < 128) v = Wq[k * 128 + n];
    else if (n < 256) v = Wk[k * 128 + (n - 128)];
    else if (n < 384) v = Wv[k * 128 + (n - 256)];
    else if (n < 512) v = Wg[k * 128 + (n - 384)];
    else if (n == 512) v = Wa[k];
    else if (n == 513) v = Wb[k];
    WcatT[idx] = f2b(v);
}

__global__ void pack_bias(const float* __restrict__ bq, const float* __restrict__ bk,
                          const float* __restrict__ bv, const float* __restrict__ bg,
                          const float* __restrict__ ba, const float* __restrict__ bb,
                          float* __restrict__ biascat)
{
    int n = threadIdx.x;
    if (n >= NPROJ) return;
    float v = 0.f;
    if      (n < 128) v = bq[n];
    else if (n < 256) v = bk[n - 128];
    else if (n < 384) v = bv[n - 256];
    else if (n < 512) v = bg[n - 384];
    else if (n == 512) v = ba[0];
    else if (n == 513) v = bb[0];
    biascat[n] = v;
}

// WoT[n][k] bf16 (Wo is [CC][DIM])
__global__ __launch_bounds__(256) void cast_wot(
    const float* __restrict__ Wo, unsigned short* __restrict__ WoT)
{
    int idx = blockIdx.x * 256 + threadIdx.x;
    if (idx >= DIMK * CC) return;
    int n = idx >> 7, k = idx & 127;
    WoT[idx] = f2b(Wo[k * DIMK + n]);
}

// ---------------------------------------------------------------------------
// BF16 MFMA GEMM: C[M][N] = A[MxK bf16] @ BT[NxK bf16]^T + bias, fp32 out.
// Tile 128(M) x 64(N), BK=32. 256 threads = 4 waves; wave w owns rows
// [w*32, w*32+32). Per wave: 2 row-tiles x 4 col-tiles of 16x16 via
// mfma_f32_16x16x32_bf16. M%128==0, N%64==0, K%32==0.
// ---------------------------------------------------------------------------
__global__ __launch_bounds__(256) void gemm_bt_bf16(
    const unsigned short* __restrict__ A, const unsigned short* __restrict__ BT,
    const float* __restrict__ bias, float* __restrict__ C,
    int M, int N, int K)
{
    __shared__ unsigned short As[4][128][8];   // [k-quad][m][j]
    __shared__ unsigned short Bs[4][64][8];    // [k-quad][n][j]
    int tid = threadIdx.x;
    int w = tid >> 6, l = tid & 63;
    int lm = l & 15, lq = l >> 4;
    int bm = blockIdx.y * 128, bn = blockIdx.x * 64;

    f32x4v acc[2][4];
#pragma unroll
    for (int rt = 0; rt < 2; rt++)
#pragma unroll
        for (int ct = 0; ct < 4; ct++) acc[rt][ct] = (f32x4v)(0.f);

    int ar = tid >> 1, ah = tid & 1;          // A stage: row ar, 16-elem half ah
    int brn = tid >> 2, bq = tid & 3;         // B stage: row brn, 8-elem quarter
    const unsigned short* Arow = A + (size_t)(bm + ar) * K + ah * 16;
    const unsigned short* Brow = BT + (size_t)(bn + brn) * K + bq * 8;

    for (int kk = 0; kk < K; kk += 32) {
        uint4 av0 = *(const uint4*)(Arow + kk);
        uint4 av1 = *(const uint4*)(Arow + kk + 8);
        uint4 bv  = *(const uint4*)(Brow + kk);
        __syncthreads();
        *(uint4*)&As[ah * 2][ar][0]     = av0;
        *(uint4*)&As[ah * 2 + 1][ar][0] = av1;
        *(uint4*)&Bs[bq][brn][0]        = bv;
        __syncthreads();
        bf16x8 af[2], bf[4];
#pragma unroll
        for (int rt = 0; rt < 2; rt++)
            __builtin_memcpy(&af[rt], &As[lq][w * 32 + rt * 16 + lm][0], 16);
#pragma unroll
        for (int ct = 0; ct < 4; ct++)
            __builtin_memcpy(&bf[ct], &Bs[lq][ct * 16 + lm][0], 16);
#pragma unroll
        for (int rt = 0; rt < 2; rt++)
#pragma unroll
            for (int ct = 0; ct < 4; ct++)
                acc[rt][ct] = __builtin_amdgcn_mfma_f32_16x16x32_bf16(
                    af[rt], bf[ct], acc[rt][ct], 0, 0, 0);
    }
#pragma unroll
    for (int rt = 0; rt < 2; rt++)
#pragma unroll
        for (int ct = 0; ct < 4; ct++) {
            int col = bn + ct * 16 + lm;
            float bcol = bias[col];
#pragma unroll
            for (int i = 0; i < 4; i++) {
                int row = bm + w * 32 + rt * 16 + lq * 4 + i;
                C[(size_t)row * N + col] = acc[rt][ct][i] + bcol;
            }
        }
}

// ---------------------------------------------------------------------------
// Post-projection (unchanged)
// ---------------------------------------------------------------------------
__global__ __launch_bounds__(64) void postproj_kernel(
    const float* __restrict__ Y, float* __restrict__ knorm,
    float* __restrict__ gbuf, float4* __restrict__ qvab)
{
    int m = blockIdx.x;
    int lane = threadIdx.x;
    int b = m >> 11, t = m & (TT - 1);
    const float* yr = Y + (size_t)m * YSTR;
    float k0 = yr[128 + lane], k1 = yr[192 + lane];
    float ss = k0 * k0 + k1 * k1;
#pragma unroll
    for (int mask = 1; mask < 64; mask <<= 1) ss += __shfl_xor(ss, mask);
    float inv = 1.0f / fmaxf(sqrtf(ss), 1e-12f);
    knorm[(size_t)m * CC + lane]      = k0 * inv;
    knorm[(size_t)m * CC + 64 + lane] = k1 * inv;
    float g0 = yr[384 + lane], g1 = yr[448 + lane];
    gbuf[(size_t)m * CC + lane]      = 1.f / (1.f + expf(-g0));
    gbuf[(size_t)m * CC + 64 + lane] = 1.f / (1.f + expf(-g1));
    float a  = 1.f / (1.f + expf(-yr[512]));
    float bb = 1.f / (1.f + expf(-yr[513]));
    {
        int i = lane;
        qvab[((size_t)(b * NG + (i >> 2)) * TT + t) * 4 + (i & 3)] =
            make_float4(yr[i], yr[256 + i], a, bb);
        i = lane + 64;
        qvab[((size_t)(b * NG + (i >> 2)) * TT + t) * 4 + (i & 3)] =
            make_float4(yr[i], yr[256 + i], a, bb);
    }
}

// ---------------------------------------------------------------------------
// Cross-lane helpers
// ---------------------------------------------------------------------------
__device__ __forceinline__ float dpp_add_xor1(float p) {
    int i = __builtin_amdgcn_mov_dpp(__float_as_int(p), 0xB1, 0xF, 0xF, true);
    return p + __int_as_float(i);
}
__device__ __forceinline__ float dpp_add_xor2(float p) {
    int i = __builtin_amdgcn_mov_dpp(__float_as_int(p), 0x4E, 0xF, 0xF, true);
    return p + __int_as_float(i);
}
__device__ __forceinline__ float dpp_add_mirror7(float p) {
    int i = __builtin_amdgcn_mov_dpp(__float_as_int(p), 0x141, 0xF, 0xF, true);
    return p + __int_as_float(i);
}
__device__ __forceinline__ float dpp_add_ror8(float p) {
    int i = __builtin_amdgcn_mov_dpp(__float_as_int(p), 0x128, 0xF, 0xF, true);
    return p + __int_as_float(i);
}
__device__ __forceinline__ int h2i(__half2 h) { int i; __builtin_memcpy(&i, &h, 4); return i; }
__device__ __forceinline__ __half2 i2h(int i) { __half2 h; __builtin_memcpy(&h, &i, 4); return h; }
__device__ __forceinline__ float2 f2mul(float2 a, float2 b) {
    return make_float2(a.x * b.x, a.y * b.y);
}
__device__ __forceinline__ float2 f2fma(float2 a, float2 b, float2 c) {
    return make_float2(fmaf(a.x, b.x, c.x), fmaf(a.y, b.y, c.y));
}

// gfx950 VALU-pipe cross-row swaps (replace ds_swizzle/ds_bpermute in the
// scan's output-reduction tail; no lgkmcnt, no LDS pipe).
// The builtins return a 2-wide machine vector: index with [0]/[1].
__device__ __forceinline__ void pl16_swap(unsigned &a, unsigned &b) {
#if __has_builtin(__builtin_amdgcn_permlane16_swap)
    auto r = __builtin_amdgcn_permlane16_swap(a, b, false, false);
    a = (unsigned)r[0]; b = (unsigned)r[1];
#else
    asm volatile("v_permlane16_swap_b32 %0, %1" : "+v"(a), "+v"(b));
#endif
}
__device__ __forceinline__ void pl32_swap(unsigned &a, unsigned &b) {
#if __has_builtin(__builtin_amdgcn_permlane32_swap)
    auto r = __builtin_amdgcn_permlane32_swap(a, b, false, false);
    a = (unsigned)r[0]; b = (unsigned)r[1];
#else
    asm volatile("v_permlane32_swap_b32 %0, %1" : "+v"(a), "+v"(b));
#endif
}

// ---------------------------------------------------------------------------
// Sequential scan. Grid = MB*NG single-wave blocks (1 wave/CU — duration is
// one wave's 2048-step critical path, so this is a latency fight).
// Changes this round:
//  * __launch_bounds__(64, 1): 1 wave/CU is structural; let the allocator
//    keep the full PFD-deep load pipeline live (old build got 108 VGPRs,
//    fewer than the prefetch buffers need -> loads were de-pipelined).
//  * Output reduction tail: ds_swizzle/ds_bpermute (24 LDS-pipe ops per
//    8-step batch, serialized ~120cy each => ~360cy/step stall) replaced by
//    permlane16_swap/permlane32_swap on the VALU pipe; also deletes all
//    keep/send cndmasks. Bit-identical arithmetic.
//    permlane16_swap: odd 16-rows of a <-> even 16-rows of b. hadd2 of the
//    pair = a[i]+a[i^16] on even rows, b[i]+b[i^16] on odd rows — same
//    placement as the old keep/send + swz16.
//    permlane32_swap: hi 32 lanes of a <-> lo 32 lanes of b. hadd2 =
//    a[i]+a[i^32] on lanes<32, b[i]+b[i^32] on lanes>=32 — same as old rb1.
// ---------------------------------------------------------------------------
#define PFD 8

template <bool ATOMIC>
__global__ __launch_bounds__(64, 1) void scan_kernel(
    const float* __restrict__ knorm, const float4* __restrict__ qvab,
    void* __restrict__ outp)
{
    int blk = blockIdx.x;
    int b = blk >> 5;
    int gi = blk & 31;
    int lane = threadIdx.x;
    int cg = lane & 15, rg = lane >> 4;
    int rb0 = rg & 1, rb1 = (rg >> 1) & 1;
    float2 s2[4];
#pragma unroll
    for (int c = 0; c < 4; c++) s2[c] = make_float2(0.f, 0.f);
    size_t mbase = (size_t)b * TT;

    const float*  knb = knorm + mbase * CC + cg * 8;
    const float4* qvb = qvab + (size_t)blk * TT * 4 + rg;

    float4 kB[PFD][2];
    float4 qB[PFD];
#pragma unroll
    for (int u = 0; u < PFD; u++) {
        kB[u][0] = *(const float4*)(knb + (size_t)u * CC);
        kB[u][1] = *(const float4*)(knb + (size_t)u * CC + 4);
        qB[u] = qvb[(size_t)u * 4];
    }

    for (int t = 0; t < TT; t += PFD) {
        __half2 pb[PFD][4];
#pragma unroll
        for (int u = 0; u < PFD; u++) {
            float2 k2[4];
            k2[0] = make_float2(kB[u][0].x, kB[u][0].y);
            k2[1] = make_float2(kB[u][0].z, kB[u][0].w);
            k2[2] = make_float2(kB[u][1].x, kB[u][1].y);
            k2[3] = make_float2(kB[u][1].z, kB[u][1].w);
            float4 qv = qB[u];
            int tp = t + u + PFD;
            if (tp < TT) {
                kB[u][0] = *(const float4*)(knb + (size_t)tp * CC);
                kB[u][1] = *(const float4*)(knb + (size_t)tp * CC + 4);
                qB[u] = qvb[(size_t)tp * 4];
            }
            float q = qv.x, v = qv.y, at = qv.z, bt = qv.w;
            float2 a0 = f2mul(s2[0], k2[0]);
            float2 a1 = f2mul(s2[1], k2[1]);
            a0 = f2fma(s2[2], k2[2], a0);
            a1 = f2fma(s2[3], k2[3], a1);
            float p = (a0.x + a1.x) + (a0.y + a1.y);
            p = dpp_add_xor1(p);
            p = dpp_add_xor2(p);
            p = dpp_add_mirror7(p);
            p = dpp_add_ror8(p);
            float cr = bt * (v - at * p);
            float2 at2 = make_float2(at, at);
            float2 cr2 = make_float2(cr, cr);
            float2 q2  = make_float2(q, q);
#pragma unroll
            for (int c = 0; c < 4; c++) {
                s2[c] = f2fma(k2[c], cr2, f2mul(s2[c], at2));
                pb[u][c] = __float22half2_rn(f2mul(q2, s2[c]));
            }
        }
        int cp = cg * 4 + rb0 * 2 + rb1;
#pragma unroll
        for (int u = 0; u < PFD; u++) {
            // reduce over rg-bit0 (lane^16): even rows end with pb[j] pair
            // sum, odd rows with pb[j+2] pair sum (matches old keep/send).
            unsigned a0 = (unsigned)h2i(pb[u][0]);
            unsigned b0 = (unsigned)h2i(pb[u][2]);
            pl16_swap(a0, b0);
            __half2 r10 = __hadd2(i2h((int)a0), i2h((int)b0));
            unsigned a1 = (unsigned)h2i(pb[u][1]);
            unsigned b1 = (unsigned)h2i(pb[u][3]);
            pl16_swap(a1, b1);
            __half2 r11 = __hadd2(i2h((int)a1), i2h((int)b1));
            // reduce over rg-bit1 (lane^32): lanes<32 end with j=0 sum,
            // lanes>=32 with j=1 sum (matches old rb1 placement).
            unsigned c0 = (unsigned)h2i(r10);
            unsigned c1 = (unsigned)h2i(r11);
            pl32_swap(c0, c1);
            __half2 r2v = __hadd2(i2h((int)c0), i2h((int)c1));
            size_t m = mbase + t + u;
            if (ATOMIC) {
                float2 f = __half22float2(r2v);
                float* op = (float*)outp + m * CC + cp * 2;
                atomicAdd(op, f.x);
                atomicAdd(op + 1, f.y);
            } else {
                ((unsigned*)outp)[((size_t)gi * MROWS + m) * 64 + cp] =
                    (unsigned)h2i(r2v);
            }
        }
    }
}

// ---------------------------------------------------------------------------
// Combine f16x2 partials over NG groups, apply gate, emit bf16 pair.
// ---------------------------------------------------------------------------
__global__ __launch_bounds__(256) void combine_kernel(
    const unsigned* __restrict__ opart,
    const float* __restrict__ gbuf, unsigned* __restrict__ ocombb)
{
    size_t idx = (size_t)blockIdx.x * 256 + threadIdx.x;  // < MROWS*64
    float sx = 0.f, sy = 0.f;
#pragma unroll
    for (int gi = 0; gi < NG; ++gi) {
        __half2 h = i2h((int)opart[(size_t)gi * MROWS * 64 + idx]);
        float2 f = __half22float2(h);
        sx += f.x; sy += f.y;
    }
    float2 g = *(const float2*)(gbuf + idx * 2);
    ocombb[idx] = f2b(sx * g.x) | ((unsigned)f2b(sy * g.y) << 16);
}

__global__ __launch_bounds__(256) void gate_kernel(
    const float* __restrict__ ocombf, const float* __restrict__ gbuf,
    unsigned short* __restrict__ ocombb)
{
    size_t idx = (size_t)blockIdx.x * 256 + threadIdx.x;  // < MROWS*CC
    ocombb[idx] = f2b(ocombf[idx] * gbuf[idx]);
}

// ---------------------------------------------------------------------------
extern "C" void kernel_launch(void* const* d_in, const int* in_sizes, int n_in,
                              void* d_out, int out_size, void* d_ws, size_t ws_size,
                              hipStream_t stream)
{
    const float* x  = (const float*)d_in[0];
    const float* Wq = (const float*)d_in[1];
    const float* bq = (const float*)d_in[2];
    const float* Wk = (const float*)d_in[3];
    const float* bk = (const float*)d_in[4];
    const float* Wv = (const float*)d_in[5];
    const float* bv = (const float*)d_in[6];
    const float* Wa = (const float*)d_in[7];
    const float* ba = (const float*)d_in[8];
    const float* Wb = (const float*)d_in[9];
    const float* bb = (const float*)d_in[10];
    const float* Wg = (const float*)d_in[11];
    const float* bg = (const float*)d_in[12];
    const float* Wo = (const float*)d_in[13];
    const float* bo = (const float*)d_in[14];
    float* out = (float*)d_out;

    // ---- workspace layout (floats), with aliasing:
    //  qvab aliases xb (xb dead after proj GEMM; qvab written by postproj)
    //  opart aliases Y and beyond (Y dead after postproj)
    //  ocombf (atomic fallback) aliases opart
    float* ws = (float*)d_ws;
    size_t off = 0;
    float* knorm   = ws + off; off += (size_t)MROWS * CC;        // 2.10M
    float* gbuf    = ws + off; off += (size_t)MROWS * CC;        // 2.10M
    unsigned* ocombb = (unsigned*)(ws + off); off += (size_t)MROWS * CC / 2;
    unsigned short* WcatT = (unsigned short*)(ws + off); off += (size_t)NPROJ * DIMK / 2;
    unsigned short* WoT   = (unsigned short*)(ws + off); off += (size_t)DIMK * CC / 2;
    float* biascat = ws + off; off += NPROJ;
    unsigned short* xb = (unsigned short*)(ws + off);
    float* qvab    = ws + off; off += (size_t)MROWS * DIMK / 2;  // 8.39M (both)
    float* Y       = ws + off;
    size_t opart_off = off;
    off += (size_t)MROWS * YSTR;                                  // Y end
    float* ocombf  = ws + opart_off;
    unsigned* opart = (unsigned*)(ws + opart_off);
    size_t opart_end = opart_off + (size_t)NG * MROWS * 64;
    size_t need_big = (opart_end > off ? opart_end : off) * sizeof(float);
    bool big = ws_size >= need_big;

    hipLaunchKernelGGL(cast_x_kernel, dim3((size_t)MROWS * DIMK / 8 / 256), dim3(256), 0, stream,
                       x, xb);
    hipLaunchKernelGGL(pack_wt, dim3(NPROJ * DIMK / 256), dim3(256), 0, stream,
                       Wq, Wk, Wv, Wg, Wa, Wb, WcatT);
    hipLaunchKernelGGL(pack_bias, dim3(1), dim3(NPROJ), 0, stream,
                       bq, bk, bv, bg, ba, bb, biascat);
    hipLaunchKernelGGL(cast_wot, dim3(DIMK * CC / 256), dim3(256), 0, stream,
                       Wo, WoT);
    // projection GEMM: Y[16384][576] = xb @ WcatT^T + biascat
    hipLaunchKernelGGL(gemm_bt_bf16, dim3(NPROJ / 64, MROWS / 128), dim3(256), 0, stream,
                       xb, WcatT, biascat, Y, MROWS, NPROJ, DIMK);
    hipLaunchKernelGGL(postproj_kernel, dim3(MROWS), dim3(64), 0, stream,
                       Y, knorm, gbuf, (float4*)qvab);
    if (big) {
        hipLaunchKernelGGL((scan_kernel<false>), dim3(MB * NG), dim3(64), 0, stream,
                           knorm, (const float4*)qvab, (void*)opart);
        hipLaunchKernelGGL(combine_kernel, dim3(MROWS * 64 / 256), dim3(256), 0, stream,
                           opart, gbuf, ocombb);
    } else {
        (void)hipMemsetAsync(ocombf, 0, (size_t)MROWS * CC * sizeof(float), stream);
        hipLaunchKernelGGL((scan_kernel<true>), dim3(MB * NG), dim3(64), 0, stream,
                           knorm, (const float4*)qvab, (void*)ocombf);
        hipLaunchKernelGGL(gate_kernel, dim3(MROWS * CC / 256), dim3(256), 0, stream,
                           ocombf, gbuf, (unsigned short*)ocombb);
    }
    // output GEMM: out[16384][1024] = ocombb @ WoT^T + bo
    hipLaunchKernelGGL(gemm_bt_bf16, dim3(DIMK / 64, MROWS / 128), dim3(256), 0, stream,
                       (const unsigned short*)ocombb, WoT, bo, out, MROWS, DIMK, CC);
}

// Round 3
// 520.407 us; speedup vs baseline: 1.3429x; 1.2442x over previous
//
#include <hip/hip_runtime.h>
#include <hip/hip_fp16.h>
#include <cstdint>

#define MB 8
#define TT 2048
#define DIMK 1024
#define CC 128
#define NG 32                 /* scan groups per batch, 4 rows each */
#define MROWS (MB*TT)         /* 16384 */
#define NPROJ 576
#define YSTR 576

using bf16x8 = __attribute__((__ext_vector_type__(8))) __bf16;
using f32x4v = __attribute__((__ext_vector_type__(4))) float;

__device__ __forceinline__ unsigned short f2b(float f) {
    unsigned u = __float_as_uint(f);
    u += 0x7fffu + ((u >> 16) & 1u);
    return (unsigned short)(u >> 16);
}

// ---------------------------------------------------------------------------
// Casts / packing
// ---------------------------------------------------------------------------
__global__ __launch_bounds__(256) void cast_x_kernel(
    const float* __restrict__ in, unsigned short* __restrict__ outp)
{
    size_t i = ((size_t)blockIdx.x * 256 + threadIdx.x) * 8;
    float4 a = *(const float4*)(in + i);
    float4 b = *(const float4*)(in + i + 4);
    uint4 r;
    r.x = f2b(a.x) | ((unsigned)f2b(a.y) << 16);
    r.y = f2b(a.z) | ((unsigned)f2b(a.w) << 16);
    r.z = f2b(b.x) | ((unsigned)f2b(b.y) << 16);
    r.w = f2b(b.z) | ((unsigned)f2b(b.w) << 16);
    *(uint4*)(outp + i) = r;
}

// WcatT[n][k] bf16, n in [0,576): 0-127 Wq, ... 512 Wa, 513 Wb, rest 0.
__global__ __launch_bounds__(256) void pack_wt(
    const float* __restrict__ Wq, const float* __restrict__ Wk,
    const float* __restrict__ Wv, const float* __restrict__ Wg,
    const float* __restrict__ Wa, const float* __restrict__ Wb,
    unsigned short* __restrict__ WcatT)
{
    int idx = blockIdx.x * 256 + threadIdx.x;
    if (idx >= NPROJ * DIMK) return;
    int n = idx >> 10, k = idx & 1023;
    float v = 0.f;
    if      (n < 128) v = Wq[k * 128 + n];
    else if (n < 256) v = Wk[k * 128 + (n - 128)];
    else if (n < 384) v = Wv[k * 128 + (n - 256)];
    else if (n < 512) v = Wg[k * 128 + (n - 384)];
    else if (n == 512) v = Wa[k];
    else if (n == 513) v = Wb[k];
    WcatT[idx] = f2b(v);
}

__global__ void pack_bias(const float* __restrict__ bq, const float* __restrict__ bk,
                          const float* __restrict__ bv, const float* __restrict__ bg,
                          const float* __restrict__ ba, const float* __restrict__ bb,
                          float* __restrict__ biascat)
{
    int n = threadIdx.x;
    if (n >= NPROJ) return;
    float v = 0.f;
    if      (n < 128) v = bq[n];
    else if (n < 256) v = bk[n - 128];
    else if (n < 384) v = bv[n - 256];
    else if (n < 512) v = bg[n - 384];
    else if (n == 512) v = ba[0];
    else if (n == 513) v = bb[0];
    biascat[n] = v;
}

// WoT[n][k] bf16 (Wo is [CC][DIM])
__global__ __launch_bounds__(256) void cast_wot(
    const float* __restrict__ Wo, unsigned short* __restrict__ WoT)
{
    int idx = blockIdx.x * 256 + threadIdx.x;
    if (idx >= DIMK * CC) return;
    int n = idx >> 7, k = idx & 127;
    WoT[idx] = f2b(Wo[k * DIMK + n]);
}

// ---------------------------------------------------------------------------
// BF16 MFMA GEMM: C[M][N] = A[MxK bf16] @ BT[NxK bf16]^T + bias, fp32 out.
// ---------------------------------------------------------------------------
__global__ __launch_bounds__(256) void gemm_bt_bf16(
    const unsigned short* __restrict__ A, const unsigned short* __restrict__ BT,
    const float* __restrict__ bias, float* __restrict__ C,
    int M, int N, int K)
{
    __shared__ unsigned short As[4][128][8];   // [k-quad][m][j]
    __shared__ unsigned short Bs[4][64][8];    // [k-quad][n][j]
    int tid = threadIdx.x;
    int w = tid >> 6, l = tid & 63;
    int lm = l & 15, lq = l >> 4;
    int bm = blockIdx.y * 128, bn = blockIdx.x * 64;

    f32x4v acc[2][4];
#pragma unroll
    for (int rt = 0; rt < 2; rt++)
#pragma unroll
        for (int ct = 0; ct < 4; ct++) acc[rt][ct] = (f32x4v)(0.f);

    int ar = tid >> 1, ah = tid & 1;          // A stage: row ar, 16-elem half ah
    int brn = tid >> 2, bq = tid & 3;         // B stage: row brn, 8-elem quarter
    const unsigned short* Arow = A + (size_t)(bm + ar) * K + ah * 16;
    const unsigned short* Brow = BT + (size_t)(bn + brn) * K + bq * 8;

    for (int kk = 0; kk < K; kk += 32) {
        uint4 av0 = *(const uint4*)(Arow + kk);
        uint4 av1 = *(const uint4*)(Arow + kk + 8);
        uint4 bv  = *(const uint4*)(Brow + kk);
        __syncthreads();
        *(uint4*)&As[ah * 2][ar][0]     = av0;
        *(uint4*)&As[ah * 2 + 1][ar][0] = av1;
        *(uint4*)&Bs[bq][brn][0]        = bv;
        __syncthreads();
        bf16x8 af[2], bf[4];
#pragma unroll
        for (int rt = 0; rt < 2; rt++)
            __builtin_memcpy(&af[rt], &As[lq][w * 32 + rt * 16 + lm][0], 16);
#pragma unroll
        for (int ct = 0; ct < 4; ct++)
            __builtin_memcpy(&bf[ct], &Bs[lq][ct * 16 + lm][0], 16);
#pragma unroll
        for (int rt = 0; rt < 2; rt++)
#pragma unroll
            for (int ct = 0; ct < 4; ct++)
                acc[rt][ct] = __builtin_amdgcn_mfma_f32_16x16x32_bf16(
                    af[rt], bf[ct], acc[rt][ct], 0, 0, 0);
    }
#pragma unroll
    for (int rt = 0; rt < 2; rt++)
#pragma unroll
        for (int ct = 0; ct < 4; ct++) {
            int col = bn + ct * 16 + lm;
            float bcol = bias[col];
#pragma unroll
            for (int i = 0; i < 4; i++) {
                int row = bm + w * 32 + rt * 16 + lq * 4 + i;
                C[(size_t)row * N + col] = acc[rt][ct][i] + bcol;
            }
        }
}

// ---------------------------------------------------------------------------
// Post-projection (unchanged)
// ---------------------------------------------------------------------------
__global__ __launch_bounds__(64) void postproj_kernel(
    const float* __restrict__ Y, float* __restrict__ knorm,
    float* __restrict__ gbuf, float4* __restrict__ qvab)
{
    int m = blockIdx.x;
    int lane = threadIdx.x;
    int b = m >> 11, t = m & (TT - 1);
    const float* yr = Y + (size_t)m * YSTR;
    float k0 = yr[128 + lane], k1 = yr[192 + lane];
    float ss = k0 * k0 + k1 * k1;
#pragma unroll
    for (int mask = 1; mask < 64; mask <<= 1) ss += __shfl_xor(ss, mask);
    float inv = 1.0f / fmaxf(sqrtf(ss), 1e-12f);
    knorm[(size_t)m * CC + lane]      = k0 * inv;
    knorm[(size_t)m * CC + 64 + lane] = k1 * inv;
    float g0 = yr[384 + lane], g1 = yr[448 + lane];
    gbuf[(size_t)m * CC + lane]      = 1.f / (1.f + expf(-g0));
    gbuf[(size_t)m * CC + 64 + lane] = 1.f / (1.f + expf(-g1));
    float a  = 1.f / (1.f + expf(-yr[512]));
    float bb = 1.f / (1.f + expf(-yr[513]));
    {
        int i = lane;
        qvab[((size_t)(b * NG + (i >> 2)) * TT + t) * 4 + (i & 3)] =
            make_float4(yr[i], yr[256 + i], a, bb);
        i = lane + 64;
        qvab[((size_t)(b * NG + (i >> 2)) * TT + t) * 4 + (i & 3)] =
            make_float4(yr[i], yr[256 + i], a, bb);
    }
}

// ---------------------------------------------------------------------------
// Cross-lane helpers
// ---------------------------------------------------------------------------
__device__ __forceinline__ float dpp_add_xor1(float p) {
    int i = __builtin_amdgcn_mov_dpp(__float_as_int(p), 0xB1, 0xF, 0xF, true);
    return p + __int_as_float(i);
}
__device__ __forceinline__ float dpp_add_xor2(float p) {
    int i = __builtin_amdgcn_mov_dpp(__float_as_int(p), 0x4E, 0xF, 0xF, true);
    return p + __int_as_float(i);
}
__device__ __forceinline__ float dpp_add_mirror7(float p) {
    int i = __builtin_amdgcn_mov_dpp(__float_as_int(p), 0x141, 0xF, 0xF, true);
    return p + __int_as_float(i);
}
__device__ __forceinline__ float dpp_add_ror8(float p) {
    int i = __builtin_amdgcn_mov_dpp(__float_as_int(p), 0x128, 0xF, 0xF, true);
    return p + __int_as_float(i);
}
__device__ __forceinline__ int h2i(__half2 h) { int i; __builtin_memcpy(&i, &h, 4); return i; }
__device__ __forceinline__ __half2 i2h(int i) { __half2 h; __builtin_memcpy(&h, &i, 4); return h; }
__device__ __forceinline__ float2 f2mul(float2 a, float2 b) {
    return make_float2(a.x * b.x, a.y * b.y);
}
__device__ __forceinline__ float2 f2fma(float2 a, float2 b, float2 c) {
    return make_float2(fmaf(a.x, b.x, c.x), fmaf(a.y, b.y, c.y));
}

// gfx950 VALU-pipe cross-row swaps (no LDS pipe, no lgkmcnt).
__device__ __forceinline__ void pl16_swap(unsigned &a, unsigned &b) {
#if __has_builtin(__builtin_amdgcn_permlane16_swap)
    auto r = __builtin_amdgcn_permlane16_swap(a, b, false, false);
    a = (unsigned)r[0]; b = (unsigned)r[1];
#else
    asm volatile("v_permlane16_swap_b32 %0, %1" : "+v"(a), "+v"(b));
#endif
}
__device__ __forceinline__ void pl32_swap(unsigned &a, unsigned &b) {
#if __has_builtin(__builtin_amdgcn_permlane32_swap)
    auto r = __builtin_amdgcn_permlane32_swap(a, b, false, false);
    a = (unsigned)r[0]; b = (unsigned)r[1];
#else
    asm volatile("v_permlane32_swap_b32 %0, %1" : "+v"(a), "+v"(b));
#endif
}

// async global->LDS, 16B/lane, 1024B/instruction. LDS dest is wave-uniform
// base + lane*16 (HW); global src is per-lane.
__device__ __forceinline__ void gload_lds16(const void* g, void* l) {
    __builtin_amdgcn_global_load_lds(
        (const __attribute__((address_space(1))) void*)g,
        (__attribute__((address_space(3))) void*)l, 16, 0, 0);
}

// ---------------------------------------------------------------------------
// Sequential scan, LDS-staged. Grid = MB*NG single-wave blocks (1 wave/CU;
// duration = one wave's 2048-step critical path -> latency fight).
//
// R3 change: global-load latency was the ~420cy/step stall (R2 post-mortem:
// VGPR=104 proved the register prefetch pipeline was de-pipelined by the
// allocator). Now k/q are staged through LDS with async global_load_lds,
// double-buffered in 32-step chunks (18 instrs/chunk), counted
// s_waitcnt vmcnt(18) (never 0 in steady state). In-flight data costs zero
// VGPRs -> prefetch depth is structural. Per-step consume is 3x ds_read_b128
// (2 k + 1 broadcast q), hand-pipelined 2-deep in named registers.
//
// k-row LDS slot permutation (both-sides-or-neither, rule 21): LDS slot j of
// each 512B row holds global slot (j<16 ? 2j : 2(j-16)+1), applied by
// pre-permuting the per-lane GLOBAL source address (LDS dest stays linear).
// Lane cg then reads its 32B as b128 at byte cg*16 and 256+cg*16 -> 2-way
// banked (free) instead of 4-way.
// ---------------------------------------------------------------------------
#define CH  32                 /* steps per chunk */
#define NCH (TT/CH)            /* 64 chunks */
#define CHLD 18                /* global_load_lds instrs per chunk: 16 k + 2 q */

template <bool ATOMIC>
__global__ __launch_bounds__(64, 1) void scan_kernel(
    const float* __restrict__ knorm, const float4* __restrict__ qvab,
    void* __restrict__ outp)
{
    __shared__ float lk[2 * CH * 128];   // 2 x 16 KiB k chunks
    __shared__ float lq[2 * CH * 16];    // 2 x 2 KiB q chunks

    int blk = blockIdx.x;
    int b = blk >> 5;
    int gi = blk & 31;
    int lane = threadIdx.x;
    int cg = lane & 15, rg = lane >> 4;
    int rb0 = rg & 1, rb1 = (rg >> 1) & 1;
    int cp = cg * 4 + rb0 * 2 + rb1;
    float2 s2[4];
#pragma unroll
    for (int c = 0; c < 4; c++) s2[c] = make_float2(0.f, 0.f);
    size_t mbase = (size_t)b * TT;

    // per-lane constant staging offsets
    int lr = lane >> 5, lj = lane & 31;
    int pj = (lj < 16) ? (2 * lj) : (2 * (lj - 16) + 1);
    size_t k_lane_off = ((size_t)lr * 32 + pj) * 16;  // bytes in 1024B window
    size_t q_lane_off = (size_t)lane * 16;

    const char* kgb = (const char*)(knorm + mbase * CC);
    const char* qgb = (const char*)(qvab + (size_t)blk * TT * 4);

#define STAGE_CHUNK(cc, bf) do {                                              \
    char* lkd = (char*)(lk + (size_t)(bf) * CH * 128);                        \
    char* lqd = (char*)(lq + (size_t)(bf) * CH * 16);                         \
    const char* kc_ = kgb + (size_t)(cc) * CH * 512;                          \
    const char* qc_ = qgb + (size_t)(cc) * CH * 64;                           \
    _Pragma("unroll")                                                         \
    for (int i_ = 0; i_ < 16; ++i_)                                           \
        gload_lds16(kc_ + (size_t)i_ * 1024 + k_lane_off, lkd + i_ * 1024);   \
    _Pragma("unroll")                                                         \
    for (int i_ = 0; i_ < 2; ++i_)                                            \
        gload_lds16(qc_ + (size_t)i_ * 1024 + q_lane_off, lqd + i_ * 1024);   \
} while (0)

#define LDK(st, ka, kb, qv) do {                                              \
    const float* rb_ = lkc + (st) * 128;                                      \
    (ka) = *(const float4*)(rb_ + cg * 4);                                    \
    (kb) = *(const float4*)(rb_ + 64 + cg * 4);                               \
    (qv) = *(const float4*)(lqc + (st) * 16 + rg * 4);                        \
} while (0)

#define KSTEP(st, ka, kb, qv) do {                                            \
    float2 k20 = make_float2((ka).x, (ka).y);                                 \
    float2 k21 = make_float2((ka).z, (ka).w);                                 \
    float2 k22 = make_float2((kb).x, (kb).y);                                 \
    float2 k23 = make_float2((kb).z, (kb).w);                                 \
    float q_ = (qv).x, v_ = (qv).y, at_ = (qv).z, bt_ = (qv).w;               \
    float2 a0_ = f2mul(s2[0], k20);                                           \
    float2 a1_ = f2mul(s2[1], k21);                                           \
    a0_ = f2fma(s2[2], k22, a0_);                                             \
    a1_ = f2fma(s2[3], k23, a1_);                                             \
    float p_ = (a0_.x + a1_.x) + (a0_.y + a1_.y);                             \
    p_ = dpp_add_xor1(p_);                                                    \
    p_ = dpp_add_xor2(p_);                                                    \
    p_ = dpp_add_mirror7(p_);                                                 \
    p_ = dpp_add_ror8(p_);                                                    \
    float cr_ = bt_ * (v_ - at_ * p_);                                        \
    float2 at2_ = make_float2(at_, at_);                                      \
    float2 cr2_ = make_float2(cr_, cr_);                                      \
    float2 q2_  = make_float2(q_, q_);                                        \
    __half2 pb0_, pb1_, pb2_, pb3_;                                           \
    s2[0] = f2fma(k20, cr2_, f2mul(s2[0], at2_));                             \
    pb0_ = __float22half2_rn(f2mul(q2_, s2[0]));                              \
    s2[1] = f2fma(k21, cr2_, f2mul(s2[1], at2_));                             \
    pb1_ = __float22half2_rn(f2mul(q2_, s2[1]));                              \
    s2[2] = f2fma(k22, cr2_, f2mul(s2[2], at2_));                             \
    pb2_ = __float22half2_rn(f2mul(q2_, s2[2]));                              \
    s2[3] = f2fma(k23, cr2_, f2mul(s2[3], at2_));                             \
    pb3_ = __float22half2_rn(f2mul(q2_, s2[3]));                              \
    unsigned A0_ = (unsigned)h2i(pb0_), B0_ = (unsigned)h2i(pb2_);            \
    pl16_swap(A0_, B0_);                                                      \
    __half2 r10_ = __hadd2(i2h((int)A0_), i2h((int)B0_));                     \
    unsigned A1_ = (unsigned)h2i(pb1_), B1_ = (unsigned)h2i(pb3_);            \
    pl16_swap(A1_, B1_);                                                      \
    __half2 r11_ = __hadd2(i2h((int)A1_), i2h((int)B1_));                     \
    unsigned C0_ = (unsigned)h2i(r10_), C1_ = (unsigned)h2i(r11_);            \
    pl32_swap(C0_, C1_);                                                      \
    __half2 r2v_ = __hadd2(i2h((int)C0_), i2h((int)C1_));                     \
    size_t m_ = mbase + (size_t)tglob + (st);                                 \
    if (ATOMIC) {                                                             \
        float2 f_ = __half22float2(r2v_);                                     \
        float* op_ = (float*)outp + m_ * CC + cp * 2;                         \
        atomicAdd(op_, f_.x);                                                 \
        atomicAdd(op_ + 1, f_.y);                                             \
    } else {                                                                  \
        ((unsigned*)outp)[((size_t)gi * MROWS + m_) * 64 + cp] =              \
            (unsigned)h2i(r2v_);                                              \
    }                                                                         \
} while (0)

    STAGE_CHUNK(0, 0);

    for (int c = 0; c < NCH; ++c) {
        int cur = c & 1;
        if (c + 1 < NCH) {
            STAGE_CHUNK(c + 1, cur ^ 1);
            asm volatile("s_waitcnt vmcnt(18)" ::: "memory");
        } else {
            asm volatile("s_waitcnt vmcnt(0)" ::: "memory");
        }
        const float* lkc = lk + (size_t)cur * CH * 128;
        const float* lqc = lq + (size_t)cur * CH * 16;
        int tglob = c * CH;

        float4 kaA, kbA, qA, kaB, kbB, qB;
        LDK(0, kaA, kbA, qA);
#pragma unroll
        for (int pp = 0; pp < CH / 2; ++pp) {
            int st = 2 * pp;
            LDK(st + 1, kaB, kbB, qB);
            KSTEP(st, kaA, kbA, qA);
            if (st + 2 < CH) LDK(st + 2, kaA, kbA, qA);
            KSTEP(st + 1, kaB, kbB, qB);
        }
    }
#undef STAGE_CHUNK
#undef LDK
#undef KSTEP
}

// ---------------------------------------------------------------------------
// Combine f16x2 partials over NG groups, apply gate, emit bf16 pair.
// ---------------------------------------------------------------------------
__global__ __launch_bounds__(256) void combine_kernel(
    const unsigned* __restrict__ opart,
    const float* __restrict__ gbuf, unsigned* __restrict__ ocombb)
{
    size_t idx = (size_t)blockIdx.x * 256 + threadIdx.x;  // < MROWS*64
    float sx = 0.f, sy = 0.f;
#pragma unroll
    for (int gi = 0; gi < NG; ++gi) {
        __half2 h = i2h((int)opart[(size_t)gi * MROWS * 64 + idx]);
        float2 f = __half22float2(h);
        sx += f.x; sy += f.y;
    }
    float2 g = *(const float2*)(gbuf + idx * 2);
    ocombb[idx] = f2b(sx * g.x) | ((unsigned)f2b(sy * g.y) << 16);
}

__global__ __launch_bounds__(256) void gate_kernel(
    const float* __restrict__ ocombf, const float* __restrict__ gbuf,
    unsigned short* __restrict__ ocombb)
{
    size_t idx = (size_t)blockIdx.x * 256 + threadIdx.x;  // < MROWS*CC
    ocombb[idx] = f2b(ocombf[idx] * gbuf[idx]);
}

// ---------------------------------------------------------------------------
extern "C" void kernel_launch(void* const* d_in, const int* in_sizes, int n_in,
                              void* d_out, int out_size, void* d_ws, size_t ws_size,
                              hipStream_t stream)
{
    const float* x  = (const float*)d_in[0];
    const float* Wq = (const float*)d_in[1];
    const float* bq = (const float*)d_in[2];
    const float* Wk = (const float*)d_in[3];
    const float* bk = (const float*)d_in[4];
    const float* Wv = (const float*)d_in[5];
    const float* bv = (const float*)d_in[6];
    const float* Wa = (const float*)d_in[7];
    const float* ba = (const float*)d_in[8];
    const float* Wb = (const float*)d_in[9];
    const float* bb = (const float*)d_in[10];
    const float* Wg = (const float*)d_in[11];
    const float* bg = (const float*)d_in[12];
    const float* Wo = (const float*)d_in[13];
    const float* bo = (const float*)d_in[14];
    float* out = (float*)d_out;

    // ---- workspace layout (floats), with aliasing:
    //  qvab aliases xb (xb dead after proj GEMM; qvab written by postproj)
    //  opart aliases Y and beyond (Y dead after postproj)
    //  ocombf (atomic fallback) aliases opart
    float* ws = (float*)d_ws;
    size_t off = 0;
    float* knorm   = ws + off; off += (size_t)MROWS * CC;        // 2.10M
    float* gbuf    = ws + off; off += (size_t)MROWS * CC;        // 2.10M
    unsigned* ocombb = (unsigned*)(ws + off); off += (size_t)MROWS * CC / 2;
    unsigned short* WcatT = (unsigned short*)(ws + off); off += (size_t)NPROJ * DIMK / 2;
    unsigned short* WoT   = (unsigned short*)(ws + off); off += (size_t)DIMK * CC / 2;
    float* biascat = ws + off; off += NPROJ;
    unsigned short* xb = (unsigned short*)(ws + off);
    float* qvab    = ws + off; off += (size_t)MROWS * DIMK / 2;  // 8.39M (both)
    float* Y       = ws + off;
    size_t opart_off = off;
    off += (size_t)MROWS * YSTR;                                  // Y end
    float* ocombf  = ws + opart_off;
    unsigned* opart = (unsigned*)(ws + opart_off);
    size_t opart_end = opart_off + (size_t)NG * MROWS * 64;
    size_t need_big = (opart_end > off ? opart_end : off) * sizeof(float);
    bool big = ws_size >= need_big;

    hipLaunchKernelGGL(cast_x_kernel, dim3((size_t)MROWS * DIMK / 8 / 256), dim3(256), 0, stream,
                       x, xb);
    hipLaunchKernelGGL(pack_wt, dim3(NPROJ * DIMK / 256), dim3(256), 0, stream,
                       Wq, Wk, Wv, Wg, Wa, Wb, WcatT);
    hipLaunchKernelGGL(pack_bias, dim3(1), dim3(NPROJ), 0, stream,
                       bq, bk, bv, bg, ba, bb, biascat);
    hipLaunchKernelGGL(cast_wot, dim3(DIMK * CC / 256), dim3(256), 0, stream,
                       Wo, WoT);
    // projection GEMM: Y[16384][576] = xb @ WcatT^T + biascat
    hipLaunchKernelGGL(gemm_bt_bf16, dim3(NPROJ / 64, MROWS / 128), dim3(256), 0, stream,
                       xb, WcatT, biascat, Y, MROWS, NPROJ, DIMK);
    hipLaunchKernelGGL(postproj_kernel, dim3(MROWS), dim3(64), 0, stream,
                       Y, knorm, gbuf, (float4*)qvab);
    if (big) {
        hipLaunchKernelGGL((scan_kernel<false>), dim3(MB * NG), dim3(64), 0, stream,
                           knorm, (const float4*)qvab, (void*)opart);
        hipLaunchKernelGGL(combine_kernel, dim3(MROWS * 64 / 256), dim3(256), 0, stream,
                           opart, gbuf, ocombb);
    } else {
        (void)hipMemsetAsync(ocombf, 0, (size_t)MROWS * CC * sizeof(float), stream);
        hipLaunchKernelGGL((scan_kernel<true>), dim3(MB * NG), dim3(64), 0, stream,
                           knorm, (const float4*)qvab, (void*)ocombf);
        hipLaunchKernelGGL(gate_kernel, dim3(MROWS * CC / 256), dim3(256), 0, stream,
                           ocombf, gbuf, (unsigned short*)ocombb);
    }
    // output GEMM: out[16384][1024] = ocombb @ WoT^T + bo
    hipLaunchKernelGGL(gemm_bt_bf16, dim3(DIMK / 64, MROWS / 128), dim3(256), 0, stream,
                       (const unsigned short*)ocombb, WoT, bo, out, MROWS, DIMK, CC);
}

// Round 4
// 470.120 us; speedup vs baseline: 1.4866x; 1.1070x over previous
//
#include <hip/hip_runtime.h>
#include <hip/hip_fp16.h>
#include <cstdint>

#define MB 8
#define TT 2048
#define DIMK 1024
#define CC 128
#define NG 32                 /* scan groups per batch, 4 rows each */
#define MROWS (MB*TT)         /* 16384 */
#define NPROJ 576
#define YSTR 576

using bf16x8 = __attribute__((__ext_vector_type__(8))) __bf16;
using f32x4v = __attribute__((__ext_vector_type__(4))) float;
using f32x2v = __attribute__((__ext_vector_type__(2))) float;

__device__ __forceinline__ unsigned short f2b(float f) {
    unsigned u = __float_as_uint(f);
    u += 0x7fffu + ((u >> 16) & 1u);
    return (unsigned short)(u >> 16);
}

// ---------------------------------------------------------------------------
// Casts / packing
// ---------------------------------------------------------------------------
__global__ __launch_bounds__(256) void cast_x_kernel(
    const float* __restrict__ in, unsigned short* __restrict__ outp)
{
    size_t i = ((size_t)blockIdx.x * 256 + threadIdx.x) * 8;
    float4 a = *(const float4*)(in + i);
    float4 b = *(const float4*)(in + i + 4);
    uint4 r;
    r.x = f2b(a.x) | ((unsigned)f2b(a.y) << 16);
    r.y = f2b(a.z) | ((unsigned)f2b(a.w) << 16);
    r.z = f2b(b.x) | ((unsigned)f2b(b.y) << 16);
    r.w = f2b(b.z) | ((unsigned)f2b(b.w) << 16);
    *(uint4*)(outp + i) = r;
}

// WcatT[n][k] bf16, n in [0,576): 0-127 Wq, ... 512 Wa, 513 Wb, rest 0.
__global__ __launch_bounds__(256) void pack_wt(
    const float* __restrict__ Wq, const float* __restrict__ Wk,
    const float* __restrict__ Wv, const float* __restrict__ Wg,
    const float* __restrict__ Wa, const float* __restrict__ Wb,
    unsigned short* __restrict__ WcatT)
{
    int idx = blockIdx.x * 256 + threadIdx.x;
    if (idx >= NPROJ * DIMK) return;
    int n = idx >> 10, k = idx & 1023;
    float v = 0.f;
    if      (n < 128) v = Wq[k * 128 + n];
    else if (n < 256) v = Wk[k * 128 + (n - 128)];
    else if (n < 384) v = Wv[k * 128 + (n - 256)];
    else if (n < 512) v = Wg[k * 128 + (n - 384)];
    else if (n == 512) v = Wa[k];
    else if (n == 513) v = Wb[k];
    WcatT[idx] = f2b(v);
}

__global__ void pack_bias(const float* __restrict__ bq, const float* __restrict__ bk,
                          const float* __restrict__ bv, const float* __restrict__ bg,
                          const float* __restrict__ ba, const float* __restrict__ bb,
                          float* __restrict__ biascat)
{
    int n = threadIdx.x;
    if (n >= NPROJ) return;
    float v = 0.f;
    if      (n < 128) v = bq[n];
    else if (n < 256) v = bk[n - 128];
    else if (n < 384) v = bv[n - 256];
    else if (n < 512) v = bg[n - 384];
    else if (n == 512) v = ba[0];
    else if (n == 513) v = bb[0];
    biascat[n] = v;
}

// WoT[n][k] bf16 (Wo is [CC][DIM])
__global__ __launch_bounds__(256) void cast_wot(
    const float* __restrict__ Wo, unsigned short* __restrict__ WoT)
{
    int idx = blockIdx.x * 256 + threadIdx.x;
    if (idx >= DIMK * CC) return;
    int n = idx >> 7, k = idx & 127;
    WoT[idx] = f2b(Wo[k * DIMK + n]);
}

// ---------------------------------------------------------------------------
// BF16 MFMA GEMM: C[M][N] = A[MxK bf16] @ BT[NxK bf16]^T + bias, fp32 out.
// ---------------------------------------------------------------------------
__global__ __launch_bounds__(256) void gemm_bt_bf16(
    const unsigned short* __restrict__ A, const unsigned short* __restrict__ BT,
    const float* __restrict__ bias, float* __restrict__ C,
    int M, int N, int K)
{
    __shared__ unsigned short As[4][128][8];   // [k-quad][m][j]
    __shared__ unsigned short Bs[4][64][8];    // [k-quad][n][j]
    int tid = threadIdx.x;
    int w = tid >> 6, l = tid & 63;
    int lm = l & 15, lq = l >> 4;
    int bm = blockIdx.y * 128, bn = blockIdx.x * 64;

    f32x4v acc[2][4];
#pragma unroll
    for (int rt = 0; rt < 2; rt++)
#pragma unroll
        for (int ct = 0; ct < 4; ct++) acc[rt][ct] = (f32x4v)(0.f);

    int ar = tid >> 1, ah = tid & 1;          // A stage: row ar, 16-elem half ah
    int brn = tid >> 2, bq = tid & 3;         // B stage: row brn, 8-elem quarter
    const unsigned short* Arow = A + (size_t)(bm + ar) * K + ah * 16;
    const unsigned short* Brow = BT + (size_t)(bn + brn) * K + bq * 8;

    for (int kk = 0; kk < K; kk += 32) {
        uint4 av0 = *(const uint4*)(Arow + kk);
        uint4 av1 = *(const uint4*)(Arow + kk + 8);
        uint4 bv  = *(const uint4*)(Brow + kk);
        __syncthreads();
        *(uint4*)&As[ah * 2][ar][0]     = av0;
        *(uint4*)&As[ah * 2 + 1][ar][0] = av1;
        *(uint4*)&Bs[bq][brn][0]        = bv;
        __syncthreads();
        bf16x8 af[2], bf[4];
#pragma unroll
        for (int rt = 0; rt < 2; rt++)
            __builtin_memcpy(&af[rt], &As[lq][w * 32 + rt * 16 + lm][0], 16);
#pragma unroll
        for (int ct = 0; ct < 4; ct++)
            __builtin_memcpy(&bf[ct], &Bs[lq][ct * 16 + lm][0], 16);
#pragma unroll
        for (int rt = 0; rt < 2; rt++)
#pragma unroll
            for (int ct = 0; ct < 4; ct++)
                acc[rt][ct] = __builtin_amdgcn_mfma_f32_16x16x32_bf16(
                    af[rt], bf[ct], acc[rt][ct], 0, 0, 0);
    }
#pragma unroll
    for (int rt = 0; rt < 2; rt++)
#pragma unroll
        for (int ct = 0; ct < 4; ct++) {
            int col = bn + ct * 16 + lm;
            float bcol = bias[col];
#pragma unroll
            for (int i = 0; i < 4; i++) {
                int row = bm + w * 32 + rt * 16 + lq * 4 + i;
                C[(size_t)row * N + col] = acc[rt][ct][i] + bcol;
            }
        }
}

// ---------------------------------------------------------------------------
// Post-projection (unchanged)
// ---------------------------------------------------------------------------
__global__ __launch_bounds__(64) void postproj_kernel(
    const float* __restrict__ Y, float* __restrict__ knorm,
    float* __restrict__ gbuf, float4* __restrict__ qvab)
{
    int m = blockIdx.x;
    int lane = threadIdx.x;
    int b = m >> 11, t = m & (TT - 1);
    const float* yr = Y + (size_t)m * YSTR;
    float k0 = yr[128 + lane], k1 = yr[192 + lane];
    float ss = k0 * k0 + k1 * k1;
#pragma unroll
    for (int mask = 1; mask < 64; mask <<= 1) ss += __shfl_xor(ss, mask);
    float inv = 1.0f / fmaxf(sqrtf(ss), 1e-12f);
    knorm[(size_t)m * CC + lane]      = k0 * inv;
    knorm[(size_t)m * CC + 64 + lane] = k1 * inv;
    float g0 = yr[384 + lane], g1 = yr[448 + lane];
    gbuf[(size_t)m * CC + lane]      = 1.f / (1.f + expf(-g0));
    gbuf[(size_t)m * CC + 64 + lane] = 1.f / (1.f + expf(-g1));
    float a  = 1.f / (1.f + expf(-yr[512]));
    float bb = 1.f / (1.f + expf(-yr[513]));
    {
        int i = lane;
        qvab[((size_t)(b * NG + (i >> 2)) * TT + t) * 4 + (i & 3)] =
            make_float4(yr[i], yr[256 + i], a, bb);
        i = lane + 64;
        qvab[((size_t)(b * NG + (i >> 2)) * TT + t) * 4 + (i & 3)] =
            make_float4(yr[i], yr[256 + i], a, bb);
    }
}

// ---------------------------------------------------------------------------
// Cross-lane helpers
// ---------------------------------------------------------------------------
__device__ __forceinline__ float dpp_add_xor1(float p) {
    int i = __builtin_amdgcn_mov_dpp(__float_as_int(p), 0xB1, 0xF, 0xF, true);
    return p + __int_as_float(i);
}
__device__ __forceinline__ float dpp_add_xor2(float p) {
    int i = __builtin_amdgcn_mov_dpp(__float_as_int(p), 0x4E, 0xF, 0xF, true);
    return p + __int_as_float(i);
}
__device__ __forceinline__ float dpp_add_mirror7(float p) {
    int i = __builtin_amdgcn_mov_dpp(__float_as_int(p), 0x141, 0xF, 0xF, true);
    return p + __int_as_float(i);
}
__device__ __forceinline__ float dpp_add_ror8(float p) {
    int i = __builtin_amdgcn_mov_dpp(__float_as_int(p), 0x128, 0xF, 0xF, true);
    return p + __int_as_float(i);
}
__device__ __forceinline__ int h2i(__half2 h) { int i; __builtin_memcpy(&i, &h, 4); return i; }
__device__ __forceinline__ __half2 i2h(int i) { __half2 h; __builtin_memcpy(&h, &i, 4); return h; }

// packed f32 helpers (lower to v_pk_mul_f32 / v_pk_fma_f32 on CDNA)
__device__ __forceinline__ f32x2v vfma2(f32x2v a, f32x2v b, f32x2v c) {
#if __has_builtin(__builtin_elementwise_fma)
    return __builtin_elementwise_fma(a, b, c);
#else
    return a * b + c;   // -ffp-contract=fast fuses per-element
#endif
}
__device__ __forceinline__ __half2 cvt2h(f32x2v v) {
    return __float22half2_rn(make_float2(v.x, v.y));
}

// gfx950 VALU-pipe cross-row swaps (no LDS pipe, no lgkmcnt).
__device__ __forceinline__ void pl16_swap(unsigned &a, unsigned &b) {
#if __has_builtin(__builtin_amdgcn_permlane16_swap)
    auto r = __builtin_amdgcn_permlane16_swap(a, b, false, false);
    a = (unsigned)r[0]; b = (unsigned)r[1];
#else
    asm volatile("v_permlane16_swap_b32 %0, %1" : "+v"(a), "+v"(b));
#endif
}
__device__ __forceinline__ void pl32_swap(unsigned &a, unsigned &b) {
#if __has_builtin(__builtin_amdgcn_permlane32_swap)
    auto r = __builtin_amdgcn_permlane32_swap(a, b, false, false);
    a = (unsigned)r[0]; b = (unsigned)r[1];
#else
    asm volatile("v_permlane32_swap_b32 %0, %1" : "+v"(a), "+v"(b));
#endif
}

// async global->LDS, 16B/lane, 1024B/instruction. LDS dest is wave-uniform
// base + lane*16 (HW); global src is per-lane.
__device__ __forceinline__ void gload_lds16(const void* g, void* l) {
    __builtin_amdgcn_global_load_lds(
        (const __attribute__((address_space(1))) void*)g,
        (__attribute__((address_space(3))) void*)l, 16, 0, 0);
}

// ---------------------------------------------------------------------------
// Sequential scan, LDS-staged. Grid = MB*NG single-wave blocks (1 wave/CU;
// duration = one wave's 2048-step critical path -> latency fight).
//
// R4 changes (R3 post-mortem: 347 cy/step = ~150 issue + ~80 chain + ~150
// residual stall; global-load latency solved by LDS staging):
//  * packed fp32 (v_pk_mul/v_pk_fma via float2 ext-vectors): halves the
//    per-step VALU instruction count (~58 -> ~38). Same fused-FMA dataflow,
//    bit-identical results.
//  * ds_read pipeline deepened to 3 steps ahead (4 rotating register sets,
//    compile-time indices via full unroll) so ds_read_b128 ~120cy latency is
//    covered by ~3 steps of issue, not ~1.
//  * steady-state chunk wait vmcnt(24) instead of vmcnt(18): tolerates the 6
//    newest global stores in flight, still guarantees (FIFO vmcnt) that the
//    current chunk's 18 staging loads have landed. c==0 uses vmcnt(18) (no
//    stores yet: 24 would not cover chunk 0's own loads); last chunk drains.
// ---------------------------------------------------------------------------
#define CH  32                 /* steps per chunk */
#define NCH (TT/CH)            /* 64 chunks */

template <bool ATOMIC>
__global__ __launch_bounds__(64, 1) void scan_kernel(
    const float* __restrict__ knorm, const float4* __restrict__ qvab,
    void* __restrict__ outp)
{
    __shared__ float lk[2 * CH * 128];   // 2 x 16 KiB k chunks
    __shared__ float lq[2 * CH * 16];    // 2 x 2 KiB q chunks

    int blk = blockIdx.x;
    int b = blk >> 5;
    int gi = blk & 31;
    int lane = threadIdx.x;
    int cg = lane & 15, rg = lane >> 4;
    int rb0 = rg & 1, rb1 = (rg >> 1) & 1;
    int cp = cg * 4 + rb0 * 2 + rb1;
    f32x2v s2[4];
#pragma unroll
    for (int c = 0; c < 4; c++) s2[c] = (f32x2v)(0.f);
    size_t mbase = (size_t)b * TT;

    // per-lane constant staging offsets
    int lr = lane >> 5, lj = lane & 31;
    int pj = (lj < 16) ? (2 * lj) : (2 * (lj - 16) + 1);
    size_t k_lane_off = ((size_t)lr * 32 + pj) * 16;  // bytes in 1024B window
    size_t q_lane_off = (size_t)lane * 16;

    const char* kgb = (const char*)(knorm + mbase * CC);
    const char* qgb = (const char*)(qvab + (size_t)blk * TT * 4);

#define STAGE_CHUNK(cc, bf) do {                                              \
    char* lkd = (char*)(lk + (size_t)(bf) * CH * 128);                        \
    char* lqd = (char*)(lq + (size_t)(bf) * CH * 16);                         \
    const char* kc_ = kgb + (size_t)(cc) * CH * 512;                          \
    const char* qc_ = qgb + (size_t)(cc) * CH * 64;                           \
    _Pragma("unroll")                                                         \
    for (int i_ = 0; i_ < 16; ++i_)                                           \
        gload_lds16(kc_ + (size_t)i_ * 1024 + k_lane_off, lkd + i_ * 1024);   \
    _Pragma("unroll")                                                         \
    for (int i_ = 0; i_ < 2; ++i_)                                            \
        gload_lds16(qc_ + (size_t)i_ * 1024 + q_lane_off, lqd + i_ * 1024);   \
} while (0)

#define LDK(st, ka, kb, qv) do {                                              \
    const float* rb_ = lkc + (st) * 128;                                      \
    (ka) = *(const f32x4v*)(rb_ + cg * 4);                                    \
    (kb) = *(const f32x4v*)(rb_ + 64 + cg * 4);                               \
    (qv) = *(const f32x4v*)(lqc + (st) * 16 + rg * 4);                        \
} while (0)

#define KSTEP(st, ka, kb, qv) do {                                            \
    f32x2v k20 = __builtin_shufflevector((ka), (ka), 0, 1);                   \
    f32x2v k21 = __builtin_shufflevector((ka), (ka), 2, 3);                   \
    f32x2v k22 = __builtin_shufflevector((kb), (kb), 0, 1);                   \
    f32x2v k23 = __builtin_shufflevector((kb), (kb), 2, 3);                   \
    float q_ = (qv).x, v_ = (qv).y, at_ = (qv).z, bt_ = (qv).w;               \
    f32x2v a0_ = s2[0] * k20;                                                 \
    f32x2v a1_ = s2[1] * k21;                                                 \
    a0_ = vfma2(s2[2], k22, a0_);                                             \
    a1_ = vfma2(s2[3], k23, a1_);                                             \
    f32x2v ps_ = a0_ + a1_;                                                   \
    float p_ = ps_.x + ps_.y;                                                 \
    p_ = dpp_add_xor1(p_);                                                    \
    p_ = dpp_add_xor2(p_);                                                    \
    p_ = dpp_add_mirror7(p_);                                                 \
    p_ = dpp_add_ror8(p_);                                                    \
    float cr_ = bt_ * (v_ - at_ * p_);                                        \
    f32x2v at2_ = {at_, at_};                                                 \
    f32x2v cr2_ = {cr_, cr_};                                                 \
    f32x2v q2_  = {q_, q_};                                                   \
    __half2 pb0_, pb1_, pb2_, pb3_;                                           \
    s2[0] = vfma2(k20, cr2_, s2[0] * at2_);                                   \
    pb0_ = cvt2h(q2_ * s2[0]);                                                \
    s2[1] = vfma2(k21, cr2_, s2[1] * at2_);                                   \
    pb1_ = cvt2h(q2_ * s2[1]);                                                \
    s2[2] = vfma2(k22, cr2_, s2[2] * at2_);                                   \
    pb2_ = cvt2h(q2_ * s2[2]);                                                \
    s2[3] = vfma2(k23, cr2_, s2[3] * at2_);                                   \
    pb3_ = cvt2h(q2_ * s2[3]);                                                \
    unsigned A0_ = (unsigned)h2i(pb0_), B0_ = (unsigned)h2i(pb2_);            \
    pl16_swap(A0_, B0_);                                                      \
    __half2 r10_ = __hadd2(i2h((int)A0_), i2h((int)B0_));                     \
    unsigned A1_ = (unsigned)h2i(pb1_), B1_ = (unsigned)h2i(pb3_);            \
    pl16_swap(A1_, B1_);                                                      \
    __half2 r11_ = __hadd2(i2h((int)A1_), i2h((int)B1_));                     \
    unsigned C0_ = (unsigned)h2i(r10_), C1_ = (unsigned)h2i(r11_);            \
    pl32_swap(C0_, C1_);                                                      \
    __half2 r2v_ = __hadd2(i2h((int)C0_), i2h((int)C1_));                     \
    size_t m_ = mbase + (size_t)tglob + (st);                                 \
    if (ATOMIC) {                                                             \
        float2 f_ = __half22float2(r2v_);                                     \
        float* op_ = (float*)outp + m_ * CC + cp * 2;                         \
        atomicAdd(op_, f_.x);                                                 \
        atomicAdd(op_ + 1, f_.y);                                             \
    } else {                                                                  \
        ((unsigned*)outp)[((size_t)gi * MROWS + m_) * 64 + cp] =              \
            (unsigned)h2i(r2v_);                                              \
    }                                                                         \
} while (0)

    STAGE_CHUNK(0, 0);

    for (int c = 0; c < NCH; ++c) {
        int cur = c & 1;
        if (c + 1 < NCH) {
            STAGE_CHUNK(c + 1, cur ^ 1);
            if (c == 0) {
                asm volatile("s_waitcnt vmcnt(18)" ::: "memory");
            } else {
                asm volatile("s_waitcnt vmcnt(24)" ::: "memory");
            }
        } else {
            asm volatile("s_waitcnt vmcnt(0)" ::: "memory");
        }
        const float* lkc = lk + (size_t)cur * CH * 128;
        const float* lqc = lq + (size_t)cur * CH * 16;
        int tglob = c * CH;

        f32x4v kaP[4], kbP[4], qvP[4];
        LDK(0, kaP[0], kbP[0], qvP[0]);
        LDK(1, kaP[1], kbP[1], qvP[1]);
        LDK(2, kaP[2], kbP[2], qvP[2]);
#pragma unroll
        for (int st = 0; st < CH; ++st) {
            if (st + 3 < CH)
                LDK(st + 3, kaP[(st + 3) & 3], kbP[(st + 3) & 3], qvP[(st + 3) & 3]);
            KSTEP(st, kaP[st & 3], kbP[st & 3], qvP[st & 3]);
        }
    }
#undef STAGE_CHUNK
#undef LDK
#undef KSTEP
}

// ---------------------------------------------------------------------------
// Combine f16x2 partials over NG groups, apply gate, emit bf16 pair.
// ---------------------------------------------------------------------------
__global__ __launch_bounds__(256) void combine_kernel(
    const unsigned* __restrict__ opart,
    const float* __restrict__ gbuf, unsigned* __restrict__ ocombb)
{
    size_t idx = (size_t)blockIdx.x * 256 + threadIdx.x;  // < MROWS*64
    float sx = 0.f, sy = 0.f;
#pragma unroll
    for (int gi = 0; gi < NG; ++gi) {
        __half2 h = i2h((int)opart[(size_t)gi * MROWS * 64 + idx]);
        float2 f = __half22float2(h);
        sx += f.x; sy += f.y;
    }
    float2 g = *(const float2*)(gbuf + idx * 2);
    ocombb[idx] = f2b(sx * g.x) | ((unsigned)f2b(sy * g.y) << 16);
}

__global__ __launch_bounds__(256) void gate_kernel(
    const float* __restrict__ ocombf, const float* __restrict__ gbuf,
    unsigned short* __restrict__ ocombb)
{
    size_t idx = (size_t)blockIdx.x * 256 + threadIdx.x;  // < MROWS*CC
    ocombb[idx] = f2b(ocombf[idx] * gbuf[idx]);
}

// ---------------------------------------------------------------------------
extern "C" void kernel_launch(void* const* d_in, const int* in_sizes, int n_in,
                              void* d_out, int out_size, void* d_ws, size_t ws_size,
                              hipStream_t stream)
{
    const float* x  = (const float*)d_in[0];
    const float* Wq = (const float*)d_in[1];
    const float* bq = (const float*)d_in[2];
    const float* Wk = (const float*)d_in[3];
    const float* bk = (const float*)d_in[4];
    const float* Wv = (const float*)d_in[5];
    const float* bv = (const float*)d_in[6];
    const float* Wa = (const float*)d_in[7];
    const float* ba = (const float*)d_in[8];
    const float* Wb = (const float*)d_in[9];
    const float* bb = (const float*)d_in[10];
    const float* Wg = (const float*)d_in[11];
    const float* bg = (const float*)d_in[12];
    const float* Wo = (const float*)d_in[13];
    const float* bo = (const float*)d_in[14];
    float* out = (float*)d_out;

    // ---- workspace layout (floats), with aliasing:
    //  qvab aliases xb (xb dead after proj GEMM; qvab written by postproj)
    //  opart aliases Y and beyond (Y dead after postproj)
    //  ocombf (atomic fallback) aliases opart
    float* ws = (float*)d_ws;
    size_t off = 0;
    float* knorm   = ws + off; off += (size_t)MROWS * CC;        // 2.10M
    float* gbuf    = ws + off; off += (size_t)MROWS * CC;        // 2.10M
    unsigned* ocombb = (unsigned*)(ws + off); off += (size_t)MROWS * CC / 2;
    unsigned short* WcatT = (unsigned short*)(ws + off); off += (size_t)NPROJ * DIMK / 2;
    unsigned short* WoT   = (unsigned short*)(ws + off); off += (size_t)DIMK * CC / 2;
    float* biascat = ws + off; off += NPROJ;
    unsigned short* xb = (unsigned short*)(ws + off);
    float* qvab    = ws + off; off += (size_t)MROWS * DIMK / 2;  // 8.39M (both)
    float* Y       = ws + off;
    size_t opart_off = off;
    off += (size_t)MROWS * YSTR;                                  // Y end
    float* ocombf  = ws + opart_off;
    unsigned* opart = (unsigned*)(ws + opart_off);
    size_t opart_end = opart_off + (size_t)NG * MROWS * 64;
    size_t need_big = (opart_end > off ? opart_end : off) * sizeof(float);
    bool big = ws_size >= need_big;

    hipLaunchKernelGGL(cast_x_kernel, dim3((size_t)MROWS * DIMK / 8 / 256), dim3(256), 0, stream,
                       x, xb);
    hipLaunchKernelGGL(pack_wt, dim3(NPROJ * DIMK / 256), dim3(256), 0, stream,
                       Wq, Wk, Wv, Wg, Wa, Wb, WcatT);
    hipLaunchKernelGGL(pack_bias, dim3(1), dim3(NPROJ), 0, stream,
                       bq, bk, bv, bg, ba, bb, biascat);
    hipLaunchKernelGGL(cast_wot, dim3(DIMK * CC / 256), dim3(256), 0, stream,
                       Wo, WoT);
    // projection GEMM: Y[16384][576] = xb @ WcatT^T + biascat
    hipLaunchKernelGGL(gemm_bt_bf16, dim3(NPROJ / 64, MROWS / 128), dim3(256), 0, stream,
                       xb, WcatT, biascat, Y, MROWS, NPROJ, DIMK);
    hipLaunchKernelGGL(postproj_kernel, dim3(MROWS), dim3(64), 0, stream,
                       Y, knorm, gbuf, (float4*)qvab);
    if (big) {
        hipLaunchKernelGGL((scan_kernel<false>), dim3(MB * NG), dim3(64), 0, stream,
                           knorm, (const float4*)qvab, (void*)opart);
        hipLaunchKernelGGL(combine_kernel, dim3(MROWS * 64 / 256), dim3(256), 0, stream,
                           opart, gbuf, ocombb);
    } else {
        (void)hipMemsetAsync(ocombf, 0, (size_t)MROWS * CC * sizeof(float), stream);
        hipLaunchKernelGGL((scan_kernel<true>), dim3(MB * NG), dim3(64), 0, stream,
                           knorm, (const float4*)qvab, (void*)ocombf);
        hipLaunchKernelGGL(gate_kernel, dim3(MROWS * CC / 256), dim3(256), 0, stream,
                           ocombf, gbuf, (unsigned short*)ocombb);
    }
    // output GEMM: out[16384][1024] = ocombb @ WoT^T + bo
    hipLaunchKernelGGL(gemm_bt_bf16, dim3(DIMK / 64, MROWS / 128), dim3(256), 0, stream,
                       (const unsigned short*)ocombb, WoT, bo, out, MROWS, DIMK, CC);
}

// Round 5
// 440.005 us; speedup vs baseline: 1.5883x; 1.0684x over previous
//
#include <hip/hip_runtime.h>
#include <hip/hip_fp16.h>
#include <cstdint>

#define MB 8
#define TT 2048
#define DIMK 1024
#define CC 128
#define NG 32                 /* scan groups per batch, 4 rows each */
#define MROWS (MB*TT)         /* 16384 */
#define NPROJ 576
#define YSTR 576

using bf16x8 = __attribute__((__ext_vector_type__(8))) __bf16;
using f32x4v = __attribute__((__ext_vector_type__(4))) float;
using f32x2v = __attribute__((__ext_vector_type__(2))) float;

__device__ __forceinline__ unsigned short f2b(float f) {
    unsigned u = __float_as_uint(f);
    u += 0x7fffu + ((u >> 16) & 1u);
    return (unsigned short)(u >> 16);
}

// ---------------------------------------------------------------------------
// Casts / packing
// ---------------------------------------------------------------------------
__global__ __launch_bounds__(256) void cast_x_kernel(
    const float* __restrict__ in, unsigned short* __restrict__ outp)
{
    size_t i = ((size_t)blockIdx.x * 256 + threadIdx.x) * 8;
    float4 a = *(const float4*)(in + i);
    float4 b = *(const float4*)(in + i + 4);
    uint4 r;
    r.x = f2b(a.x) | ((unsigned)f2b(a.y) << 16);
    r.y = f2b(a.z) | ((unsigned)f2b(a.w) << 16);
    r.z = f2b(b.x) | ((unsigned)f2b(b.y) << 16);
    r.w = f2b(b.z) | ((unsigned)f2b(b.w) << 16);
    *(uint4*)(outp + i) = r;
}

// WcatT[n][k] bf16, n in [0,576): 0-127 Wq, ... 512 Wa, 513 Wb, rest 0.
__global__ __launch_bounds__(256) void pack_wt(
    const float* __restrict__ Wq, const float* __restrict__ Wk,
    const float* __restrict__ Wv, const float* __restrict__ Wg,
    const float* __restrict__ Wa, const float* __restrict__ Wb,
    unsigned short* __restrict__ WcatT)
{
    int idx = blockIdx.x * 256 + threadIdx.x;
    if (idx >= NPROJ * DIMK) return;
    int n = idx >> 10, k = idx & 1023;
    float v = 0.f;
    if      (n < 128) v = Wq[k * 128 + n];
    else if (n < 256) v = Wk[k * 128 + (n - 128)];
    else if (n < 384) v = Wv[k * 128 + (n - 256)];
    else if (n < 512) v = Wg[k * 128 + (n - 384)];
    else if (n == 512) v = Wa[k];
    else if (n == 513) v = Wb[k];
    WcatT[idx] = f2b(v);
}

__global__ void pack_bias(const float* __restrict__ bq, const float* __restrict__ bk,
                          const float* __restrict__ bv, const float* __restrict__ bg,
                          const float* __restrict__ ba, const float* __restrict__ bb,
                          float* __restrict__ biascat)
{
    int n = threadIdx.x;
    if (n >= NPROJ) return;
    float v = 0.f;
    if      (n < 128) v = bq[n];
    else if (n < 256) v = bk[n - 128];
    else if (n < 384) v = bv[n - 256];
    else if (n < 512) v = bg[n - 384];
    else if (n == 512) v = ba[0];
    else if (n == 513) v = bb[0];
    biascat[n] = v;
}

// WoT[n][k] bf16 (Wo is [CC][DIM])
__global__ __launch_bounds__(256) void cast_wot(
    const float* __restrict__ Wo, unsigned short* __restrict__ WoT)
{
    int idx = blockIdx.x * 256 + threadIdx.x;
    if (idx >= DIMK * CC) return;
    int n = idx >> 7, k = idx & 127;
    WoT[idx] = f2b(Wo[k * DIMK + n]);
}

// ---------------------------------------------------------------------------
// BF16 MFMA GEMM: C[M][N] = A[MxK bf16] @ BT[NxK bf16]^T + bias, fp32 out.
// ---------------------------------------------------------------------------
__global__ __launch_bounds__(256) void gemm_bt_bf16(
    const unsigned short* __restrict__ A, const unsigned short* __restrict__ BT,
    const float* __restrict__ bias, float* __restrict__ C,
    int M, int N, int K)
{
    __shared__ unsigned short As[4][128][8];   // [k-quad][m][j]
    __shared__ unsigned short Bs[4][64][8];    // [k-quad][n][j]
    int tid = threadIdx.x;
    int w = tid >> 6, l = tid & 63;
    int lm = l & 15, lq = l >> 4;
    int bm = blockIdx.y * 128, bn = blockIdx.x * 64;

    f32x4v acc[2][4];
#pragma unroll
    for (int rt = 0; rt < 2; rt++)
#pragma unroll
        for (int ct = 0; ct < 4; ct++) acc[rt][ct] = (f32x4v)(0.f);

    int ar = tid >> 1, ah = tid & 1;          // A stage: row ar, 16-elem half ah
    int brn = tid >> 2, bq = tid & 3;         // B stage: row brn, 8-elem quarter
    const unsigned short* Arow = A + (size_t)(bm + ar) * K + ah * 16;
    const unsigned short* Brow = BT + (size_t)(bn + brn) * K + bq * 8;

    for (int kk = 0; kk < K; kk += 32) {
        uint4 av0 = *(const uint4*)(Arow + kk);
        uint4 av1 = *(const uint4*)(Arow + kk + 8);
        uint4 bv  = *(const uint4*)(Brow + kk);
        __syncthreads();
        *(uint4*)&As[ah * 2][ar][0]     = av0;
        *(uint4*)&As[ah * 2 + 1][ar][0] = av1;
        *(uint4*)&Bs[bq][brn][0]        = bv;
        __syncthreads();
        bf16x8 af[2], bf[4];
#pragma unroll
        for (int rt = 0; rt < 2; rt++)
            __builtin_memcpy(&af[rt], &As[lq][w * 32 + rt * 16 + lm][0], 16);
#pragma unroll
        for (int ct = 0; ct < 4; ct++)
            __builtin_memcpy(&bf[ct], &Bs[lq][ct * 16 + lm][0], 16);
#pragma unroll
        for (int rt = 0; rt < 2; rt++)
#pragma unroll
            for (int ct = 0; ct < 4; ct++)
                acc[rt][ct] = __builtin_amdgcn_mfma_f32_16x16x32_bf16(
                    af[rt], bf[ct], acc[rt][ct], 0, 0, 0);
    }
#pragma unroll
    for (int rt = 0; rt < 2; rt++)
#pragma unroll
        for (int ct = 0; ct < 4; ct++) {
            int col = bn + ct * 16 + lm;
            float bcol = bias[col];
#pragma unroll
            for (int i = 0; i < 4; i++) {
                int row = bm + w * 32 + rt * 16 + lq * 4 + i;
                C[(size_t)row * N + col] = acc[rt][ct][i] + bcol;
            }
        }
}

// ---------------------------------------------------------------------------
// Post-projection (unchanged)
// ---------------------------------------------------------------------------
__global__ __launch_bounds__(64) void postproj_kernel(
    const float* __restrict__ Y, float* __restrict__ knorm,
    float* __restrict__ gbuf, float4* __restrict__ qvab)
{
    int m = blockIdx.x;
    int lane = threadIdx.x;
    int b = m >> 11, t = m & (TT - 1);
    const float* yr = Y + (size_t)m * YSTR;
    float k0 = yr[128 + lane], k1 = yr[192 + lane];
    float ss = k0 * k0 + k1 * k1;
#pragma unroll
    for (int mask = 1; mask < 64; mask <<= 1) ss += __shfl_xor(ss, mask);
    float inv = 1.0f / fmaxf(sqrtf(ss), 1e-12f);
    knorm[(size_t)m * CC + lane]      = k0 * inv;
    knorm[(size_t)m * CC + 64 + lane] = k1 * inv;
    float g0 = yr[384 + lane], g1 = yr[448 + lane];
    gbuf[(size_t)m * CC + lane]      = 1.f / (1.f + expf(-g0));
    gbuf[(size_t)m * CC + 64 + lane] = 1.f / (1.f + expf(-g1));
    float a  = 1.f / (1.f + expf(-yr[512]));
    float bb = 1.f / (1.f + expf(-yr[513]));
    {
        int i = lane;
        qvab[((size_t)(b * NG + (i >> 2)) * TT + t) * 4 + (i & 3)] =
            make_float4(yr[i], yr[256 + i], a, bb);
        i = lane + 64;
        qvab[((size_t)(b * NG + (i >> 2)) * TT + t) * 4 + (i & 3)] =
            make_float4(yr[i], yr[256 + i], a, bb);
    }
}

// ---------------------------------------------------------------------------
// Cross-lane helpers
// ---------------------------------------------------------------------------
__device__ __forceinline__ float dpp_add_xor1(float p) {
    int i = __builtin_amdgcn_mov_dpp(__float_as_int(p), 0xB1, 0xF, 0xF, true);
    return p + __int_as_float(i);
}
__device__ __forceinline__ float dpp_add_xor2(float p) {
    int i = __builtin_amdgcn_mov_dpp(__float_as_int(p), 0x4E, 0xF, 0xF, true);
    return p + __int_as_float(i);
}
__device__ __forceinline__ float dpp_add_mirror7(float p) {
    int i = __builtin_amdgcn_mov_dpp(__float_as_int(p), 0x141, 0xF, 0xF, true);
    return p + __int_as_float(i);
}
__device__ __forceinline__ float dpp_add_ror8(float p) {
    int i = __builtin_amdgcn_mov_dpp(__float_as_int(p), 0x128, 0xF, 0xF, true);
    return p + __int_as_float(i);
}
__device__ __forceinline__ int h2i(__half2 h) { int i; __builtin_memcpy(&i, &h, 4); return i; }
__device__ __forceinline__ __half2 i2h(int i) { __half2 h; __builtin_memcpy(&h, &i, 4); return h; }

// packed f32 helpers (lower to v_pk_mul_f32 / v_pk_fma_f32 on CDNA)
__device__ __forceinline__ f32x2v vfma2(f32x2v a, f32x2v b, f32x2v c) {
#if __has_builtin(__builtin_elementwise_fma)
    return __builtin_elementwise_fma(a, b, c);
#else
    return a * b + c;
#endif
}
__device__ __forceinline__ __half2 cvt2h(f32x2v v) {
    return __float22half2_rn(make_float2(v.x, v.y));
}

// gfx950 VALU-pipe cross-row swaps (no LDS pipe, no lgkmcnt).
__device__ __forceinline__ void pl16_swap(unsigned &a, unsigned &b) {
#if __has_builtin(__builtin_amdgcn_permlane16_swap)
    auto r = __builtin_amdgcn_permlane16_swap(a, b, false, false);
    a = (unsigned)r[0]; b = (unsigned)r[1];
#else
    asm volatile("v_permlane16_swap_b32 %0, %1" : "+v"(a), "+v"(b));
#endif
}
__device__ __forceinline__ void pl32_swap(unsigned &a, unsigned &b) {
#if __has_builtin(__builtin_amdgcn_permlane32_swap)
    auto r = __builtin_amdgcn_permlane32_swap(a, b, false, false);
    a = (unsigned)r[0]; b = (unsigned)r[1];
#else
    asm volatile("v_permlane32_swap_b32 %0, %1" : "+v"(a), "+v"(b));
#endif
}
// reduce helpers: p + p[lane^16], p + p[lane^32] (copy + swap + add)
__device__ __forceinline__ float pl16_add(float p) {
    unsigned a = __float_as_uint(p), b = a;
    pl16_swap(a, b);
    return __uint_as_float(a) + __uint_as_float(b);
}
__device__ __forceinline__ float pl32_add(float p) {
    unsigned a = __float_as_uint(p), b = a;
    pl32_swap(a, b);
    return __uint_as_float(a) + __uint_as_float(b);
}

// async global->LDS, 16B/lane, 1024B/instruction.
__device__ __forceinline__ void gload_lds16(const void* g, void* l) {
    __builtin_amdgcn_global_load_lds(
        (const __attribute__((address_space(1))) void*)g,
        (__attribute__((address_space(3))) void*)l, 16, 0, 0);
}

// ---------------------------------------------------------------------------
// Sequential scan, 4 waves/block (one state-row per wave -> all 4 SIMDs of a
// CU busy; R4 post-mortem showed 1-wave scan was issue-bound on 1 SIMD with
// 3 idle). Grid = MB*NG = 256 blocks x 256 threads.
//
//  * wave w owns row 4*gi+w; lane l owns state cols 2l, 2l+1 (f32x2).
//  * per step: ds_read_b64 k (imm offset), uniform ds_read_b128 qvab,
//    pk_mul dot, 6-stage full-wave reduce (4 DPP + pl16 + pl32 swap-adds),
//    cr via hoisted b*a / b*v, pk state update, cvt -> ds_write_b32 partial.
//  * per chunk (32 steps): async-staged k (16KB, 4 gload_lds/wave) + qvab
//    (2KB, wave 0), double-buffered; counted per-wave vmcnt (4 at c<2, 12
//    steady covering 8 combine-stores + next stage, 8 at last chunk).
//  * 4-row combine once per chunk through double-buffered LDS outbuf with
//    hadd2 tree (w0+w1)+(w2+w3) == old permlane tree order; raw s_barrier +
//    lgkmcnt(0) (NOT __syncthreads -- would drain vmcnt pipeline).
// ---------------------------------------------------------------------------
#define CH  32                 /* steps per chunk */
#define NCH (TT/CH)            /* 64 chunks */

template <bool ATOMIC>
__global__ __launch_bounds__(256, 1) void scan_kernel(
    const float* __restrict__ knorm, const float4* __restrict__ qvab,
    void* __restrict__ outp)
{
    __shared__ float lk[2 * CH * 128];        // 2 x 16 KiB k chunks
    __shared__ float lq[2 * CH * 16];         // 2 x 2 KiB qvab chunks
    __shared__ unsigned outb[2 * 4 * CH * 64]; // 2 x 32 KiB partial buffers

    int blk = blockIdx.x;
    int b = blk >> 5;
    int gi = blk & 31;
    int tid = threadIdx.x;
    int w = tid >> 6, lane = tid & 63;
    f32x2v s2v = (f32x2v)(0.f);
    size_t mbase = (size_t)b * TT;

    const char* kgb = (const char*)(knorm + mbase * CC);
    const char* qgb = (const char*)(qvab + (size_t)blk * TT * 4);
    size_t lane16 = (size_t)lane * 16;

#define STAGE_CHUNK(cc, bf) do {                                              \
    char* lkd = (char*)lk + (size_t)(bf) * (CH * 512) + (size_t)w * 4096;     \
    const char* kc_ = kgb + (size_t)(cc) * (CH * 512) + (size_t)w * 4096;     \
    _Pragma("unroll")                                                         \
    for (int i_ = 0; i_ < 4; ++i_)                                            \
        gload_lds16(kc_ + (size_t)i_ * 1024 + lane16, lkd + i_ * 1024);       \
    if (w == 0) {                                                             \
        char* lqd = (char*)lq + (size_t)(bf) * (CH * 64);                     \
        const char* qc_ = qgb + (size_t)(cc) * (CH * 64);                     \
        gload_lds16(qc_ + lane16, lqd);                                       \
        gload_lds16(qc_ + 1024 + lane16, lqd + 1024);                         \
    }                                                                         \
} while (0)

#define LDK(st, sl) do {                                                      \
    kP[sl] = *(const f32x2v*)(lkc + (st) * 128 + lane * 2);                   \
    qP[sl] = *(const f32x4v*)(lqc + (st) * 16 + w * 4);                       \
} while (0)

#define KSTEP(st, sl) do {                                                    \
    f32x2v k2 = kP[sl];                                                       \
    f32x4v qv = qP[sl];                                                       \
    float q_ = qv[0], v_ = qv[1], at_ = qv[2], bt_ = qv[3];                   \
    f32x2v ps_ = s2v * k2;                                                    \
    float p_ = ps_[0] + ps_[1];                                               \
    p_ = dpp_add_xor1(p_);                                                    \
    p_ = dpp_add_xor2(p_);                                                    \
    p_ = dpp_add_mirror7(p_);                                                 \
    p_ = dpp_add_ror8(p_);                                                    \
    p_ = pl16_add(p_);                                                        \
    p_ = pl32_add(p_);                                                        \
    float ba_ = at_ * bt_, bv_ = bt_ * v_;                                    \
    float cr_ = fmaf(-ba_, p_, bv_);                                          \
    f32x2v at2_ = {at_, at_};                                                 \
    f32x2v cr2_ = {cr_, cr_};                                                 \
    f32x2v q2_  = {q_, q_};                                                   \
    s2v = vfma2(k2, cr2_, s2v * at2_);                                        \
    __half2 pb_ = cvt2h(q2_ * s2v);                                           \
    obw[(st) * 64] = (unsigned)h2i(pb_);                                      \
} while (0)

#define COMBINE(cc) do {                                                      \
    const unsigned* ob_ = outb + (size_t)((cc) & 1) * (4 * CH * 64);          \
    int tg_ = (cc) * CH;                                                      \
    _Pragma("unroll")                                                         \
    for (int j_ = 0; j_ < 8; ++j_) {                                          \
        int slot_ = tid + 256 * j_;                                           \
        int st_ = slot_ >> 6, ln_ = slot_ & 63;                               \
        __half2 h0_ = i2h((int)ob_[(0 * CH + st_) * 64 + ln_]);               \
        __half2 h1_ = i2h((int)ob_[(1 * CH + st_) * 64 + ln_]);               \
        __half2 h2_ = i2h((int)ob_[(2 * CH + st_) * 64 + ln_]);               \
        __half2 h3_ = i2h((int)ob_[(3 * CH + st_) * 64 + ln_]);               \
        __half2 r_ = __hadd2(__hadd2(h0_, h1_), __hadd2(h2_, h3_));           \
        size_t m_ = mbase + tg_ + st_;                                        \
        if (ATOMIC) {                                                         \
            float2 f_ = __half22float2(r_);                                   \
            float* op_ = (float*)outp + m_ * CC + ln_ * 2;                    \
            atomicAdd(op_, f_.x);                                             \
            atomicAdd(op_ + 1, f_.y);                                         \
        } else {                                                              \
            ((unsigned*)outp)[((size_t)gi * MROWS + m_) * 64 + ln_] =         \
                (unsigned)h2i(r_);                                            \
        }                                                                     \
    }                                                                         \
} while (0)

    STAGE_CHUNK(0, 0);

    for (int c = 0; c < NCH; ++c) {
        int cur = c & 1;
        if (c + 1 < NCH) STAGE_CHUNK(c + 1, cur ^ 1);
        // wait for chunk c's staging (per-wave FIFO vmcnt; never drain to 0)
        if (c < 2) {
            asm volatile("s_waitcnt vmcnt(4)" ::: "memory");
        } else if (c + 1 < NCH) {
            asm volatile("s_waitcnt vmcnt(12)" ::: "memory");
        } else {
            asm volatile("s_waitcnt vmcnt(8)" ::: "memory");
        }
        asm volatile("s_waitcnt lgkmcnt(0)" ::: "memory");
        __builtin_amdgcn_s_barrier();
        if (c > 0) COMBINE(c - 1);

        const float* lkc = lk + (size_t)cur * CH * 128;
        const float* lqc = lq + (size_t)cur * CH * 16;
        unsigned* obw = outb + (size_t)(cur * 4 + w) * CH * 64 + lane;

        f32x2v kP[4];
        f32x4v qP[4];
        LDK(0, 0); LDK(1, 1); LDK(2, 2);
#pragma unroll
        for (int st = 0; st < CH; ++st) {
            if (st + 3 < CH) LDK(st + 3, (st + 3) & 3);
            KSTEP(st, st & 3);
        }
    }
    asm volatile("s_waitcnt lgkmcnt(0)" ::: "memory");
    __builtin_amdgcn_s_barrier();
    COMBINE(NCH - 1);
#undef STAGE_CHUNK
#undef LDK
#undef KSTEP
#undef COMBINE
}

// ---------------------------------------------------------------------------
// Combine f16x2 partials over NG groups, apply gate, emit bf16 pair.
// ---------------------------------------------------------------------------
__global__ __launch_bounds__(256) void combine_kernel(
    const unsigned* __restrict__ opart,
    const float* __restrict__ gbuf, unsigned* __restrict__ ocombb)
{
    size_t idx = (size_t)blockIdx.x * 256 + threadIdx.x;  // < MROWS*64
    float sx = 0.f, sy = 0.f;
#pragma unroll
    for (int gi = 0; gi < NG; ++gi) {
        __half2 h = i2h((int)opart[(size_t)gi * MROWS * 64 + idx]);
        float2 f = __half22float2(h);
        sx += f.x; sy += f.y;
    }
    float2 g = *(const float2*)(gbuf + idx * 2);
    ocombb[idx] = f2b(sx * g.x) | ((unsigned)f2b(sy * g.y) << 16);
}

__global__ __launch_bounds__(256) void gate_kernel(
    const float* __restrict__ ocombf, const float* __restrict__ gbuf,
    unsigned short* __restrict__ ocombb)
{
    size_t idx = (size_t)blockIdx.x * 256 + threadIdx.x;  // < MROWS*CC
    ocombb[idx] = f2b(ocombf[idx] * gbuf[idx]);
}

// ---------------------------------------------------------------------------
extern "C" void kernel_launch(void* const* d_in, const int* in_sizes, int n_in,
                              void* d_out, int out_size, void* d_ws, size_t ws_size,
                              hipStream_t stream)
{
    const float* x  = (const float*)d_in[0];
    const float* Wq = (const float*)d_in[1];
    const float* bq = (const float*)d_in[2];
    const float* Wk = (const float*)d_in[3];
    const float* bk = (const float*)d_in[4];
    const float* Wv = (const float*)d_in[5];
    const float* bv = (const float*)d_in[6];
    const float* Wa = (const float*)d_in[7];
    const float* ba = (const float*)d_in[8];
    const float* Wb = (const float*)d_in[9];
    const float* bb = (const float*)d_in[10];
    const float* Wg = (const float*)d_in[11];
    const float* bg = (const float*)d_in[12];
    const float* Wo = (const float*)d_in[13];
    const float* bo = (const float*)d_in[14];
    float* out = (float*)d_out;

    // ---- workspace layout (floats), with aliasing:
    //  qvab aliases xb (xb dead after proj GEMM; qvab written by postproj)
    //  opart aliases Y and beyond (Y dead after postproj)
    //  ocombf (atomic fallback) aliases opart
    float* ws = (float*)d_ws;
    size_t off = 0;
    float* knorm   = ws + off; off += (size_t)MROWS * CC;        // 2.10M
    float* gbuf    = ws + off; off += (size_t)MROWS * CC;        // 2.10M
    unsigned* ocombb = (unsigned*)(ws + off); off += (size_t)MROWS * CC / 2;
    unsigned short* WcatT = (unsigned short*)(ws + off); off += (size_t)NPROJ * DIMK / 2;
    unsigned short* WoT   = (unsigned short*)(ws + off); off += (size_t)DIMK * CC / 2;
    float* biascat = ws + off; off += NPROJ;
    unsigned short* xb = (unsigned short*)(ws + off);
    float* qvab    = ws + off; off += (size_t)MROWS * DIMK / 2;  // 8.39M (both)
    float* Y       = ws + off;
    size_t opart_off = off;
    off += (size_t)MROWS * YSTR;                                  // Y end
    float* ocombf  = ws + opart_off;
    unsigned* opart = (unsigned*)(ws + opart_off);
    size_t opart_end = opart_off + (size_t)NG * MROWS * 64;
    size_t need_big = (opart_end > off ? opart_end : off) * sizeof(float);
    bool big = ws_size >= need_big;

    hipLaunchKernelGGL(cast_x_kernel, dim3((size_t)MROWS * DIMK / 8 / 256), dim3(256), 0, stream,
                       x, xb);
    hipLaunchKernelGGL(pack_wt, dim3(NPROJ * DIMK / 256), dim3(256), 0, stream,
                       Wq, Wk, Wv, Wg, Wa, Wb, WcatT);
    hipLaunchKernelGGL(pack_bias, dim3(1), dim3(NPROJ), 0, stream,
                       bq, bk, bv, bg, ba, bb, biascat);
    hipLaunchKernelGGL(cast_wot, dim3(DIMK * CC / 256), dim3(256), 0, stream,
                       Wo, WoT);
    // projection GEMM: Y[16384][576] = xb @ WcatT^T + biascat
    hipLaunchKernelGGL(gemm_bt_bf16, dim3(NPROJ / 64, MROWS / 128), dim3(256), 0, stream,
                       xb, WcatT, biascat, Y, MROWS, NPROJ, DIMK);
    hipLaunchKernelGGL(postproj_kernel, dim3(MROWS), dim3(64), 0, stream,
                       Y, knorm, gbuf, (float4*)qvab);
    if (big) {
        hipLaunchKernelGGL((scan_kernel<false>), dim3(MB * NG), dim3(256), 0, stream,
                           knorm, (const float4*)qvab, (void*)opart);
        hipLaunchKernelGGL(combine_kernel, dim3(MROWS * 64 / 256), dim3(256), 0, stream,
                           opart, gbuf, ocombb);
    } else {
        (void)hipMemsetAsync(ocombf, 0, (size_t)MROWS * CC * sizeof(float), stream);
        hipLaunchKernelGGL((scan_kernel<true>), dim3(MB * NG), dim3(256), 0, stream,
                           knorm, (const float4*)qvab, (void*)ocombf);
        hipLaunchKernelGGL(gate_kernel, dim3(MROWS * CC / 256), dim3(256), 0, stream,
                           ocombf, gbuf, (unsigned short*)ocombb);
    }
    // output GEMM: out[16384][1024] = ocombb @ WoT^T + bo
    hipLaunchKernelGGL(gemm_bt_bf16, dim3(DIMK / 64, MROWS / 128), dim3(256), 0, stream,
                       (const unsigned short*)ocombb, WoT, bo, out, MROWS, DIMK, CC);
}